// Round 1
// baseline (1050.434 us; speedup 1.0000x reference)
//
#include <hip/hip_runtime.h>
#include <math.h>

#define TB 8
#define TT 2048
#define TD 64
#define TK 5
#define TPAD 12
#define EPSBN 1e-5f
#define UMAX 4096

// ws layout (float offsets)
#define OFF_TREND 0
#define OFF_S     1048576
#define OFF_R     2097152
#define OFF_IDX   2105344
#define OFF_W     2105384
#define OFF_WT1   2105424
#define OFF_WT2   2142288
#define OFF_ZROW  2179152
#define OFF_H1    2179216
#define OFF_Y     12664976
// total 17907856 floats = 71.6 MB

// ---------------- prep: transpose weights to [tap][ci][co], zero row ----------------
__global__ void k_prep(const float* __restrict__ w1, const float* __restrict__ w2,
                       float* __restrict__ wt1, float* __restrict__ wt2, float* __restrict__ zrow)
{
    int i = blockIdx.x * 256 + threadIdx.x;
    if (i < 64) zrow[i] = 0.f;
    if (i < 36864) {
        int co = i / 576, rem = i - co * 576, ci = rem / 9, tap = rem - ci * 9;
        float a = w1[i], b = w2[i];
        int d = (tap * 64 + ci) * 64 + co;
        wt1[d] = a; wt2[d] = b;
    }
}

// ---------------- trend (AvgPool1d count_include_pad=False) + seasonal ----------------
__global__ __launch_bounds__(256) void k_trend(const float* __restrict__ x,
                                               float* __restrict__ trend, float* __restrict__ s)
{
    int gid = blockIdx.x * 256 + threadIdx.x;      // B*T*D = 2^20 threads
    int c = gid & 63; int t = (gid >> 6) & (TT - 1); int b = gid >> 17;
    int lo = t - TPAD; if (lo < 0) lo = 0;
    int hi = t + TPAD + 1; if (hi > TT) hi = TT;
    const float* base = x + ((size_t)b * TT) * TD + c;
    float sum = 0.f;
    for (int tt = lo; tt < hi; ++tt) sum += base[(size_t)tt * TD];
    float tr = sum / (float)(hi - lo);
    trend[gid] = tr;
    s[gid] = x[gid] - tr;
}

// ---------------- circular autocorrelation, lags 1..1024 ----------------
// block: (lag-group of 8, batch). 256 threads = 64 channels x 4 t-stripes.
__global__ __launch_bounds__(256) void k_autocorr(const float* __restrict__ s, float* __restrict__ r)
{
    int b = blockIdx.y;
    int l0 = blockIdx.x * 8 + 1;                   // lags l0..l0+7
    const float* sb = s + (size_t)b * TT * TD;
    int c = threadIdx.x & 63;
    int tg = threadIdx.x >> 6;
    int t0 = tg * 512;
    float acc[8] = {0,0,0,0,0,0,0,0};
    float win[8];
    #pragma unroll
    for (int m = 0; m < 8; ++m) win[m] = sb[(((t0 + l0 + m) & (TT - 1)) << 6) + c];
    for (int t = t0; t < t0 + 512; t += 8) {
        #pragma unroll
        for (int jj = 0; jj < 8; ++jj) {
            float a = sb[((t + jj) << 6) + c];
            #pragma unroll
            for (int j = 0; j < 8; ++j) acc[j] = fmaf(a, win[(jj + j) & 7], acc[j]);
            win[jj] = sb[(((t + jj + 8 + l0) & (TT - 1)) << 6) + c];
        }
    }
    __shared__ float red[256];
    #pragma unroll
    for (int j = 0; j < 8; ++j) {
        red[threadIdx.x] = acc[j];
        __syncthreads();
        for (int off = 128; off; off >>= 1) {
            if (threadIdx.x < off) red[threadIdx.x] += red[threadIdx.x + off];
            __syncthreads();
        }
        if (threadIdx.x == 0) r[(size_t)b * 1024 + (l0 - 1 + j)] = red[0] * (1.0f / 64.0f);
        __syncthreads();
    }
}

// ---------------- top-5 with symmetric-pair expansion + softmax ----------------
__global__ __launch_bounds__(256) void k_topk(const float* __restrict__ r,
                                              int* __restrict__ selidx, float* __restrict__ selw)
{
    int b = blockIdx.x;
    __shared__ float v[1024];
    __shared__ float redv[256]; __shared__ int redi[256];
    __shared__ int s_idx[6]; __shared__ float s_val[6]; __shared__ int slots;
    for (int i = threadIdx.x; i < 1024; i += 256) v[i] = r[(size_t)b * 1024 + i];  // v[i] = r at lag i+1
    if (threadIdx.x == 0) slots = 0;
    __syncthreads();
    for (int round = 0; round < 5; ++round) {
        if (slots >= 5) break;
        float bv = -INFINITY; int bi = 1 << 30;
        for (int i = threadIdx.x; i < 1024; i += 256) {
            float val = v[i];
            if (val > bv) { bv = val; bi = i; }    // ascending i -> first (lowest) index on tie
        }
        redv[threadIdx.x] = bv; redi[threadIdx.x] = bi;
        __syncthreads();
        for (int off = 128; off; off >>= 1) {
            if (threadIdx.x < off) {
                float ov = redv[threadIdx.x + off]; int oi = redi[threadIdx.x + off];
                float mv = redv[threadIdx.x];       int mi = redi[threadIdx.x];
                if (ov > mv || (ov == mv && oi < mi)) { redv[threadIdx.x] = ov; redi[threadIdx.x] = oi; }
            }
            __syncthreads();
        }
        if (threadIdx.x == 0) {
            int lag = redi[0] + 1; float val = redv[0];
            s_idx[slots] = lag; s_val[slots] = val; slots++;
            if (slots < 5 && lag < 1024) { s_idx[slots] = 2048 - lag; s_val[slots] = val; slots++; }
            v[lag - 1] = -INFINITY;
        }
        __syncthreads();
    }
    if (threadIdx.x == 0) {
        float mx = -INFINITY;
        for (int i = 0; i < 5; ++i) mx = fmaxf(mx, s_val[i]);
        float e[5], sum = 0.f;
        for (int i = 0; i < 5; ++i) { e[i] = expf(s_val[i] - mx); sum += e[i]; }
        for (int i = 0; i < 5; ++i) { selidx[b * TK + i] = s_idx[i]; selw[b * TK + i] = e[i] / sum; }
    }
}

// ---------------- conv1 on folded grid + BN1 + GELU -> h1 ----------------
// block: 16 u-rows, 256 threads = 64 co x 4 wave-slots, each thread 4 rows.
__global__ __launch_bounds__(256) void k_conv1(
    const float* __restrict__ s, const float* __restrict__ wt1,
    const float* __restrict__ g1, const float* __restrict__ b1,
    const float* __restrict__ m1, const float* __restrict__ v1,
    const int* __restrict__ sel, const float* __restrict__ zrow,
    float* __restrict__ h1)
{
    int b = blockIdx.z, k = blockIdx.y;
    int p = sel[b * TK + k];
    int cyc = (TT + p - 1) / p;
    int U = cyc * p;                                  // 2048..4094
    int u0 = blockIdx.x * 16;
    if (u0 >= U) return;                              // uniform exit before barriers
    int co = threadIdx.x & 63;
    int wslot = threadIdx.x >> 6;
    __shared__ float WL[4096];

    int uu[4]; int ru[4], cu[4]; bool act[4];
    #pragma unroll
    for (int j = 0; j < 4; ++j) {
        int u = u0 + wslot * 4 + j;
        uu[j] = u; act[j] = (u < U);
        int uc = act[j] ? u : 0;
        ru[j] = uc / p; cu[j] = uc - ru[j] * p;
    }
    float acc[4] = {0.f, 0.f, 0.f, 0.f};
    const float* sb = s + (size_t)b * TT * TD;

    for (int tap = 0; tap < 9; ++tap) {
        for (int i = threadIdx.x; i < 4096; i += 256) WL[i] = wt1[tap * 4096 + i];
        __syncthreads();
        int dr = tap / 3 - 1, dc = tap % 3 - 1;
        const float* grow[4];
        #pragma unroll
        for (int j = 0; j < 4; ++j) {
            int rr = ru[j] + dr, cc = cu[j] + dc;
            bool valid = act[j] && (rr >= 0) && (rr < cyc) && (cc >= 0) && (cc < p);
            int un = uu[j] + dr * p + dc;
            int vn = (un < TT) ? un : (2 * TT - 2 - un);      // reflect
            int sr = (vn + p) & (TT - 1);                     // roll by -p, T pow2
            grow[j] = valid ? (sb + (size_t)sr * TD) : zrow;
        }
        #pragma unroll 16
        for (int ci = 0; ci < 64; ++ci) {
            float wv = WL[(ci << 6) + co];
            #pragma unroll
            for (int j = 0; j < 4; ++j) acc[j] = fmaf(grow[j][ci], wv, acc[j]);
        }
        __syncthreads();
    }
    float scale = g1[co] * rsqrtf(v1[co] + EPSBN);
    float bias  = b1[co] - m1[co] * scale;
    float* hout = h1 + (size_t)(b * TK + k) * UMAX * TD;
    #pragma unroll
    for (int j = 0; j < 4; ++j) {
        if (act[j]) {
            float z = acc[j] * scale + bias;
            float gel = 0.5f * z * (1.0f + erff(z * 0.70710678118654752f));
            hout[(size_t)uu[j] * TD + co] = gel;
        }
    }
}

// ---------------- conv2 + BN2 + residual(g) -> y (rows < T only) ----------------
__global__ __launch_bounds__(256) void k_conv2(
    const float* __restrict__ s, const float* __restrict__ h1,
    const float* __restrict__ wt2,
    const float* __restrict__ g2, const float* __restrict__ b2,
    const float* __restrict__ m2, const float* __restrict__ v2,
    const int* __restrict__ sel, const float* __restrict__ zrow,
    float* __restrict__ y)
{
    int b = blockIdx.z, k = blockIdx.y;
    int p = sel[b * TK + k];
    int cyc = (TT + p - 1) / p;
    int u0 = blockIdx.x * 16;                         // < 2048 always (grid=128)
    int co = threadIdx.x & 63;
    int wslot = threadIdx.x >> 6;
    __shared__ float WL[4096];

    int uu[4], ru[4], cu[4];
    #pragma unroll
    for (int j = 0; j < 4; ++j) {
        int u = u0 + wslot * 4 + j;
        uu[j] = u; ru[j] = u / p; cu[j] = u - ru[j] * p;
    }
    float acc[4] = {0.f, 0.f, 0.f, 0.f};
    const float* hin = h1 + (size_t)(b * TK + k) * UMAX * TD;

    for (int tap = 0; tap < 9; ++tap) {
        for (int i = threadIdx.x; i < 4096; i += 256) WL[i] = wt2[tap * 4096 + i];
        __syncthreads();
        int dr = tap / 3 - 1, dc = tap % 3 - 1;
        const float* grow[4];
        #pragma unroll
        for (int j = 0; j < 4; ++j) {
            int rr = ru[j] + dr, cc = cu[j] + dc;
            bool valid = (rr >= 0) && (rr < cyc) && (cc >= 0) && (cc < p);
            int un = uu[j] + dr * p + dc;
            int unc = valid ? un : 0;
            grow[j] = valid ? (hin + (size_t)unc * TD) : zrow;
        }
        #pragma unroll 16
        for (int ci = 0; ci < 64; ++ci) {
            float wv = WL[(ci << 6) + co];
            #pragma unroll
            for (int j = 0; j < 4; ++j) acc[j] = fmaf(grow[j][ci], wv, acc[j]);
        }
        __syncthreads();
    }
    float scale = g2[co] * rsqrtf(v2[co] + EPSBN);
    float bias  = b2[co] - m2[co] * scale;
    const float* sb = s + (size_t)b * TT * TD;
    float* yout = y + (size_t)(b * TK + k) * TT * TD;
    #pragma unroll
    for (int j = 0; j < 4; ++j) {
        int u = uu[j];
        int sr = (u + p) & (TT - 1);                  // u<T -> reflect is identity
        float gval = sb[(size_t)sr * TD + co];
        float z = acc[j] * scale + bias;
        yout[(size_t)u * TD + co] = gval + z;
    }
}

// ---------------- combine: x + trend + sum_k w_k * y_k ----------------
__global__ __launch_bounds__(256) void k_combine(const float* __restrict__ x,
                                                 const float* __restrict__ trend,
                                                 const float* __restrict__ y,
                                                 const float* __restrict__ selw,
                                                 float* __restrict__ out)
{
    int gid = blockIdx.x * 256 + threadIdx.x;
    int c = gid & 63; int t = (gid >> 6) & (TT - 1); int b = gid >> 17;
    float acc = x[gid] + trend[gid];
    #pragma unroll
    for (int k = 0; k < TK; ++k) {
        acc += selw[b * TK + k] * y[(((size_t)(b * TK + k)) * TT + t) * TD + c];
    }
    out[gid] = acc;
}

extern "C" void kernel_launch(void* const* d_in, const int* in_sizes, int n_in,
                              void* d_out, int out_size, void* d_ws, size_t ws_size,
                              hipStream_t stream)
{
    const float* x  = (const float*)d_in[0];
    const float* w1 = (const float*)d_in[1];
    const float* w2 = (const float*)d_in[2];
    const float* g1 = (const float*)d_in[3];
    const float* b1 = (const float*)d_in[4];
    const float* m1 = (const float*)d_in[5];
    const float* v1 = (const float*)d_in[6];
    const float* g2 = (const float*)d_in[7];
    const float* b2 = (const float*)d_in[8];
    const float* m2 = (const float*)d_in[9];
    const float* v2 = (const float*)d_in[10];

    float* ws    = (float*)d_ws;
    float* trend = ws + OFF_TREND;
    float* s     = ws + OFF_S;
    float* r     = ws + OFF_R;
    int*   sel   = (int*)(ws + OFF_IDX);
    float* selw  = ws + OFF_W;
    float* wt1   = ws + OFF_WT1;
    float* wt2   = ws + OFF_WT2;
    float* zrow  = ws + OFF_ZROW;
    float* h1    = ws + OFF_H1;
    float* y     = ws + OFF_Y;
    float* out   = (float*)d_out;

    k_prep    <<<dim3(144),        dim3(256), 0, stream>>>(w1, w2, wt1, wt2, zrow);
    k_trend   <<<dim3(4096),       dim3(256), 0, stream>>>(x, trend, s);
    k_autocorr<<<dim3(128, TB),    dim3(256), 0, stream>>>(s, r);
    k_topk    <<<dim3(TB),         dim3(256), 0, stream>>>(r, sel, selw);
    k_conv1   <<<dim3(256, TK, TB), dim3(256), 0, stream>>>(s, wt1, g1, b1, m1, v1, sel, zrow, h1);
    k_conv2   <<<dim3(128, TK, TB), dim3(256), 0, stream>>>(s, h1, wt2, g2, b2, m2, v2, sel, zrow, y);
    k_combine <<<dim3(4096),       dim3(256), 0, stream>>>(x, trend, y, selw, out);
}

// Round 3
// 211.453 us; speedup vs baseline: 4.9677x; 4.9677x over previous
//
#include <hip/hip_runtime.h>
#include <hip/hip_bf16.h>
#include <math.h>

#define TB 8
#define TT 2048
#define TD 64
#define TK 5
#define TPAD 12
#define EPSBN 1e-5f
#define UMAX 4096

typedef __attribute__((ext_vector_type(8))) short short8;
typedef __attribute__((ext_vector_type(4))) float f32x4;

// ws layout (float offsets)
#define OFF_TREND 0
#define OFF_S     1048576
#define OFF_R     2097152
#define OFF_IDX   2105344
#define OFF_W     2105384
#define OFF_WT1   2105424
#define OFF_WT2   2123856
#define OFF_G     2142288
#define OFF_H1    7385168
#define OFF_Y     12628048
// end 17870928 floats = 71.5 MB

// ---------------- weights -> WT[co][tap*64+ci] bf16 ----------------
__global__ void k_prep_w(const float* __restrict__ w1, const float* __restrict__ w2,
                         __hip_bfloat16* __restrict__ wt1, __hip_bfloat16* __restrict__ wt2)
{
    int i = blockIdx.x * 256 + threadIdx.x;
    if (i < 36864) {
        int co = i / 576, rem = i - co * 576, tap = rem >> 6, ci = rem & 63;
        int src = (co * 64 + ci) * 9 + tap;
        wt1[i] = __float2bfloat16(w1[src]);
        wt2[i] = __float2bfloat16(w2[src]);
    }
}

// ---------------- trend (AvgPool1d count_include_pad=False) + seasonal ----------------
__global__ __launch_bounds__(256) void k_trend(const float* __restrict__ x,
                                               float* __restrict__ trend, float* __restrict__ s)
{
    int gid = blockIdx.x * 256 + threadIdx.x;      // B*T*D = 2^20 threads
    int c = gid & 63; int t = (gid >> 6) & (TT - 1); int b = gid >> 17;
    int lo = t - TPAD; if (lo < 0) lo = 0;
    int hi = t + TPAD + 1; if (hi > TT) hi = TT;
    const float* base = x + ((size_t)b * TT) * TD + c;
    float sum = 0.f;
    for (int tt = lo; tt < hi; ++tt) sum += base[(size_t)tt * TD];
    float tr = sum / (float)(hi - lo);
    trend[gid] = tr;
    s[gid] = x[gid] - tr;
}

// ---------------- circular autocorrelation, lags 1..1024 (exact f32) ----------------
__global__ __launch_bounds__(256) void k_autocorr(const float* __restrict__ s, float* __restrict__ r)
{
    int b = blockIdx.y;
    int l0 = blockIdx.x * 8 + 1;                   // lags l0..l0+7
    const float* sb = s + (size_t)b * TT * TD;
    int c = threadIdx.x & 63;
    int tg = threadIdx.x >> 6;
    int t0 = tg * 512;
    float acc[8] = {0,0,0,0,0,0,0,0};
    float win[8];
    #pragma unroll
    for (int m = 0; m < 8; ++m) win[m] = sb[(((t0 + l0 + m) & (TT - 1)) << 6) + c];
    for (int t = t0; t < t0 + 512; t += 8) {
        #pragma unroll
        for (int jj = 0; jj < 8; ++jj) {
            float a = sb[((t + jj) << 6) + c];
            #pragma unroll
            for (int j = 0; j < 8; ++j) acc[j] = fmaf(a, win[(jj + j) & 7], acc[j]);
            win[jj] = sb[(((t + jj + 8 + l0) & (TT - 1)) << 6) + c];
        }
    }
    __shared__ float red[256];
    #pragma unroll
    for (int j = 0; j < 8; ++j) {
        red[threadIdx.x] = acc[j];
        __syncthreads();
        for (int off = 128; off; off >>= 1) {
            if (threadIdx.x < off) red[threadIdx.x] += red[threadIdx.x + off];
            __syncthreads();
        }
        if (threadIdx.x == 0) r[(size_t)b * 1024 + (l0 - 1 + j)] = red[0] * (1.0f / 64.0f);
        __syncthreads();
    }
}

// ---------------- top-5 with symmetric-pair expansion + softmax ----------------
__global__ __launch_bounds__(256) void k_topk(const float* __restrict__ r,
                                              int* __restrict__ selidx, float* __restrict__ selw)
{
    int b = blockIdx.x;
    __shared__ float v[1024];
    __shared__ float redv[256]; __shared__ int redi[256];
    __shared__ int s_idx[6]; __shared__ float s_val[6]; __shared__ int slots;
    for (int i = threadIdx.x; i < 1024; i += 256) v[i] = r[(size_t)b * 1024 + i];
    if (threadIdx.x == 0) slots = 0;
    __syncthreads();
    for (int round = 0; round < 5; ++round) {
        if (slots >= 5) break;
        float bv = -INFINITY; int bi = 1 << 30;
        for (int i = threadIdx.x; i < 1024; i += 256) {
            float val = v[i];
            if (val > bv) { bv = val; bi = i; }
        }
        redv[threadIdx.x] = bv; redi[threadIdx.x] = bi;
        __syncthreads();
        for (int off = 128; off; off >>= 1) {
            if (threadIdx.x < off) {
                float ov = redv[threadIdx.x + off]; int oi = redi[threadIdx.x + off];
                float mv = redv[threadIdx.x];       int mi = redi[threadIdx.x];
                if (ov > mv || (ov == mv && oi < mi)) { redv[threadIdx.x] = ov; redi[threadIdx.x] = oi; }
            }
            __syncthreads();
        }
        if (threadIdx.x == 0) {
            int lag = redi[0] + 1; float val = redv[0];
            s_idx[slots] = lag; s_val[slots] = val; slots++;
            if (slots < 5 && lag < 1024) { s_idx[slots] = 2048 - lag; s_val[slots] = val; slots++; }
            v[lag - 1] = -INFINITY;
        }
        __syncthreads();
    }
    if (threadIdx.x == 0) {
        float mx = -INFINITY;
        for (int i = 0; i < 5; ++i) mx = fmaxf(mx, s_val[i]);
        float e[5], sum = 0.f;
        for (int i = 0; i < 5; ++i) { e[i] = expf(s_val[i] - mx); sum += e[i]; }
        for (int i = 0; i < 5; ++i) { selidx[b * TK + i] = s_idx[i]; selw[b * TK + i] = e[i] / sum; }
    }
}

// ---------------- g_buf[b,k][u][c] = bf16(s[b][(reflect(u)+p)%T][c]), all 4096 rows ----------------
__global__ __launch_bounds__(256) void k_gather(const float* __restrict__ s,
                                                const int* __restrict__ sel,
                                                __hip_bfloat16* __restrict__ g_buf)
{
    int b = blockIdx.z, k = blockIdx.y;
    int p = sel[b * TK + k];
    int cg = (threadIdx.x & 15) * 4;
    int ui = threadIdx.x >> 4;
    const float* sb = s + (size_t)b * TT * TD;
    __hip_bfloat16* gb = g_buf + (size_t)(b * TK + k) * (UMAX * TD);
    int u0 = blockIdx.x * 256;
    for (int it = 0; it < 16; ++it) {
        int u = u0 + it * 16 + ui;
        int v = (u < TT) ? u : (2 * TT - 2 - u);
        if (v < 0) v = 0;
        int sr = (v + p) & (TT - 1);
        const float4 f = *(const float4*)(sb + (size_t)sr * TD + cg);
        ushort4 o;
        __hip_bfloat16 t;
        t = __float2bfloat16(f.x); o.x = *(unsigned short*)&t;
        t = __float2bfloat16(f.y); o.y = *(unsigned short*)&t;
        t = __float2bfloat16(f.z); o.z = *(unsigned short*)&t;
        t = __float2bfloat16(f.w); o.w = *(unsigned short*)&t;
        *(ushort4*)((unsigned short*)gb + (size_t)u * TD + cg) = o;
    }
}

// ---------------- conv1 as MFMA GEMM: h1[u,co] = gelu(bn1(sum_k G[u,k] WT1[co,k])) ----------------
// block = 128 u-rows, 4 waves; wave = 32 u x 64 co. K = 9 taps x 64 ci.
__global__ __launch_bounds__(256) void k_mm1(
    const short* __restrict__ g_buf, const short* __restrict__ wt,
    const float* __restrict__ g1, const float* __restrict__ b1,
    const float* __restrict__ m1, const float* __restrict__ v1,
    const int* __restrict__ sel, __hip_bfloat16* __restrict__ h1)
{
    int b = blockIdx.z, k = blockIdx.y;
    int p = sel[b * TK + k];
    int cyc = (TT + p - 1) / p;
    int U = cyc * p;
    int u_blk = blockIdx.x * 128;
    if (u_blk >= U) return;
    int lane = threadIdx.x & 63;
    int w = threadIdx.x >> 6;
    int lr = lane & 15;
    int lk = (lane >> 4) * 8;
    int row0 = u_blk + w * 32 + lr;
    int row1 = row0 + 16;
    int r0 = row0 / p, c0 = row0 - r0 * p;
    int r1 = row1 / p, c1 = row1 - r1 * p;
    const short* gb = g_buf + (size_t)(b * TK + k) * (UMAX * TD);
    f32x4 acc[2][4] = {};
    short8 zero = {};
    #pragma unroll
    for (int kb = 0; kb < 18; ++kb) {
        const int tap = kb >> 1;
        const int dr = tap / 3 - 1, dc = tap % 3 - 1;
        const int koff = tap * 64 + (kb & 1) * 32 + lk;   // weight K-offset (576-axis)
        const int aoff = (kb & 1) * 32 + lk;              // A channel offset (64-axis)
        int doff = dr * p + dc;
        int un0 = row0 + doff, un1 = row1 + doff;
        bool val0 = ((unsigned)(r0 + dr) < (unsigned)cyc) && ((unsigned)(c0 + dc) < (unsigned)p);
        bool val1 = ((unsigned)(r1 + dr) < (unsigned)cyc) && ((unsigned)(c1 + dc) < (unsigned)p);
        int uc0 = min(max(un0, 0), UMAX - 1);
        int uc1 = min(max(un1, 0), UMAX - 1);
        short8 a0 = *(const short8*)(gb + (size_t)uc0 * TD + aoff);
        short8 a1 = *(const short8*)(gb + (size_t)uc1 * TD + aoff);
        if (!val0) a0 = zero;
        if (!val1) a1 = zero;
        #pragma unroll
        for (int nt = 0; nt < 4; ++nt) {
            short8 bf = *(const short8*)(wt + (size_t)(nt * 16 + lr) * 576 + koff);
            acc[0][nt] = __builtin_amdgcn_mfma_f32_16x16x32_bf16(a0, bf, acc[0][nt], 0, 0, 0);
            acc[1][nt] = __builtin_amdgcn_mfma_f32_16x16x32_bf16(a1, bf, acc[1][nt], 0, 0, 0);
        }
    }
    __hip_bfloat16* ho = h1 + (size_t)(b * TK + k) * (UMAX * TD);
    int ug = (lane >> 4) * 4;
    #pragma unroll
    for (int nt = 0; nt < 4; ++nt) {
        int co = nt * 16 + lr;
        float scale = g1[co] * rsqrtf(v1[co] + EPSBN);
        float bias = b1[co] - m1[co] * scale;
        #pragma unroll
        for (int rs = 0; rs < 2; ++rs) {
            int ub = u_blk + w * 32 + rs * 16 + ug;
            #pragma unroll
            for (int q = 0; q < 4; ++q) {
                int u = ub + q;
                if (u < U) {
                    float z = acc[rs][nt][q] * scale + bias;
                    float ge = 0.5f * z * (1.0f + erff(z * 0.70710678118654752f));
                    ho[(size_t)u * TD + co] = __float2bfloat16(ge);
                }
            }
        }
    }
}

// ---------------- conv2 as MFMA GEMM + BN2 + residual -> y (f32, rows < T) ----------------
__global__ __launch_bounds__(256) void k_mm2(
    const short* __restrict__ h1, const short* __restrict__ wt,
    const float* __restrict__ s,
    const float* __restrict__ g2, const float* __restrict__ b2,
    const float* __restrict__ m2, const float* __restrict__ v2,
    const int* __restrict__ sel, float* __restrict__ y)
{
    int b = blockIdx.z, k = blockIdx.y;
    int p = sel[b * TK + k];
    int cyc = (TT + p - 1) / p;
    int u_blk = blockIdx.x * 128;
    int lane = threadIdx.x & 63;
    int w = threadIdx.x >> 6;
    int lr = lane & 15;
    int lk = (lane >> 4) * 8;
    int row0 = u_blk + w * 32 + lr;
    int row1 = row0 + 16;
    int r0 = row0 / p, c0 = row0 - r0 * p;
    int r1 = row1 / p, c1 = row1 - r1 * p;
    const short* hb = h1 + (size_t)(b * TK + k) * (UMAX * TD);
    f32x4 acc[2][4] = {};
    short8 zero = {};
    #pragma unroll
    for (int kb = 0; kb < 18; ++kb) {
        const int tap = kb >> 1;
        const int dr = tap / 3 - 1, dc = tap % 3 - 1;
        const int koff = tap * 64 + (kb & 1) * 32 + lk;   // weight K-offset (576-axis)
        const int aoff = (kb & 1) * 32 + lk;              // A channel offset (64-axis)
        int doff = dr * p + dc;
        int un0 = row0 + doff, un1 = row1 + doff;
        bool val0 = ((unsigned)(r0 + dr) < (unsigned)cyc) && ((unsigned)(c0 + dc) < (unsigned)p);
        bool val1 = ((unsigned)(r1 + dr) < (unsigned)cyc) && ((unsigned)(c1 + dc) < (unsigned)p);
        int uc0 = min(max(un0, 0), UMAX - 1);
        int uc1 = min(max(un1, 0), UMAX - 1);
        short8 a0 = *(const short8*)(hb + (size_t)uc0 * TD + aoff);
        short8 a1 = *(const short8*)(hb + (size_t)uc1 * TD + aoff);
        if (!val0) a0 = zero;
        if (!val1) a1 = zero;
        #pragma unroll
        for (int nt = 0; nt < 4; ++nt) {
            short8 bf = *(const short8*)(wt + (size_t)(nt * 16 + lr) * 576 + koff);
            acc[0][nt] = __builtin_amdgcn_mfma_f32_16x16x32_bf16(a0, bf, acc[0][nt], 0, 0, 0);
            acc[1][nt] = __builtin_amdgcn_mfma_f32_16x16x32_bf16(a1, bf, acc[1][nt], 0, 0, 0);
        }
    }
    const float* sb = s + (size_t)b * TT * TD;
    float* yo = y + (size_t)(b * TK + k) * TT * TD;
    int ug = (lane >> 4) * 4;
    #pragma unroll
    for (int nt = 0; nt < 4; ++nt) {
        int co = nt * 16 + lr;
        float scale = g2[co] * rsqrtf(v2[co] + EPSBN);
        float bias = b2[co] - m2[co] * scale;
        #pragma unroll
        for (int rs = 0; rs < 2; ++rs) {
            int ub = u_blk + w * 32 + rs * 16 + ug;
            #pragma unroll
            for (int q = 0; q < 4; ++q) {
                int u = ub + q;                       // < 2048 always
                int sr = (u + p) & (TT - 1);          // reflect is identity for u < T
                float gval = sb[(size_t)sr * TD + co];
                float z = acc[rs][nt][q] * scale + bias;
                yo[(size_t)u * TD + co] = gval + z;
            }
        }
    }
}

// ---------------- combine: x + trend + sum_k w_k * y_k ----------------
__global__ __launch_bounds__(256) void k_combine(const float* __restrict__ x,
                                                 const float* __restrict__ trend,
                                                 const float* __restrict__ y,
                                                 const float* __restrict__ selw,
                                                 float* __restrict__ out)
{
    int gid = blockIdx.x * 256 + threadIdx.x;
    int c = gid & 63; int t = (gid >> 6) & (TT - 1); int b = gid >> 17;
    float acc = x[gid] + trend[gid];
    #pragma unroll
    for (int k = 0; k < TK; ++k) {
        acc += selw[b * TK + k] * y[(((size_t)(b * TK + k)) * TT + t) * TD + c];
    }
    out[gid] = acc;
}

extern "C" void kernel_launch(void* const* d_in, const int* in_sizes, int n_in,
                              void* d_out, int out_size, void* d_ws, size_t ws_size,
                              hipStream_t stream)
{
    const float* x  = (const float*)d_in[0];
    const float* w1 = (const float*)d_in[1];
    const float* w2 = (const float*)d_in[2];
    const float* g1 = (const float*)d_in[3];
    const float* b1 = (const float*)d_in[4];
    const float* m1 = (const float*)d_in[5];
    const float* v1 = (const float*)d_in[6];
    const float* g2 = (const float*)d_in[7];
    const float* b2 = (const float*)d_in[8];
    const float* m2 = (const float*)d_in[9];
    const float* v2 = (const float*)d_in[10];

    float* ws    = (float*)d_ws;
    float* trend = ws + OFF_TREND;
    float* s     = ws + OFF_S;
    float* r     = ws + OFF_R;
    int*   sel   = (int*)(ws + OFF_IDX);
    float* selw  = ws + OFF_W;
    __hip_bfloat16* wt1 = (__hip_bfloat16*)(ws + OFF_WT1);
    __hip_bfloat16* wt2 = (__hip_bfloat16*)(ws + OFF_WT2);
    __hip_bfloat16* gbuf= (__hip_bfloat16*)(ws + OFF_G);
    __hip_bfloat16* h1  = (__hip_bfloat16*)(ws + OFF_H1);
    float* y     = ws + OFF_Y;
    float* out   = (float*)d_out;

    k_prep_w  <<<dim3(144),         dim3(256), 0, stream>>>(w1, w2, wt1, wt2);
    k_trend   <<<dim3(4096),        dim3(256), 0, stream>>>(x, trend, s);
    k_autocorr<<<dim3(128, TB),     dim3(256), 0, stream>>>(s, r);
    k_topk    <<<dim3(TB),          dim3(256), 0, stream>>>(r, sel, selw);
    k_gather  <<<dim3(16, TK, TB),  dim3(256), 0, stream>>>(s, sel, gbuf);
    k_mm1     <<<dim3(32, TK, TB),  dim3(256), 0, stream>>>((const short*)gbuf, (const short*)wt1,
                                                            g1, b1, m1, v1, sel, h1);
    k_mm2     <<<dim3(16, TK, TB),  dim3(256), 0, stream>>>((const short*)h1, (const short*)wt2, s,
                                                            g2, b2, m2, v2, sel, y);
    k_combine <<<dim3(4096),        dim3(256), 0, stream>>>(x, trend, y, selw, out);
}